// Round 14
// baseline (858.208 us; speedup 1.0000x reference)
//
#include <hip/hip_runtime.h>

typedef _Float16 half_t;
typedef _Float16 half2_t __attribute__((ext_vector_type(2)));
typedef _Float16 half4_t __attribute__((ext_vector_type(4)));
typedef _Float16 half8_t __attribute__((ext_vector_type(8)));
typedef float float4_t __attribute__((ext_vector_type(4)));

// Problem constants
#define BB 64
#define TT 512
#define EE 128
#define HPP 128
#define KK 32
#define MTOT (BB*TT)     // 32768
#define NWID 1024        // stacked fwd(512)+bwd(512) gate rows, gate-interleaved per dir

// barrier that drains ONLY LDS ops (z prefetch + h global stores stay in flight)
__device__ __forceinline__ void lds_barrier() {
    asm volatile("s_waitcnt lgkmcnt(0)\n\ts_barrier" ::: "memory");
}

__device__ __forceinline__ float fast_sigmoid(float x) {
    return __builtin_amdgcn_rcpf(1.f + __expf(-x));     // v_exp + v_rcp, no div sequence
}
__device__ __forceinline__ float fast_tanh(float x) {
    return 1.f - 2.f * __builtin_amdgcn_rcpf(__expf(2.f * x) + 1.f);
}
__device__ __forceinline__ float readlane_f(float v, int lane) {
    return __builtin_bit_cast(float, __builtin_amdgcn_readlane(__builtin_bit_cast(int, v), lane));
}

// ---------------------------------------------------------------- pack weights fp32->fp16 + embed gather + lengths (merged)
__global__ void k_pack(const float* __restrict__ wi0f, const float* __restrict__ wi0b,
                       const float* __restrict__ wi1f, const float* __restrict__ wi1b,
                       const float* __restrict__ w_out,
                       const int* __restrict__ x, const float* __restrict__ embed,
                       half_t* __restrict__ WP0, half_t* __restrict__ WP1,
                       half_t* __restrict__ WO, half_t* __restrict__ e16,
                       int* __restrict__ lens) {
    // lengths: blocks 0..63, one block per sequence
    if (blockIdx.x < BB) {
        __shared__ int cnt;
        if (threadIdx.x == 0) cnt = 0;
        __syncthreads();
        int local = 0;
        for (int t = threadIdx.x; t < TT; t += blockDim.x)
            local += (x[blockIdx.x * TT + t] > 0) ? 1 : 0;
        atomicAdd(&cnt, local);
        __syncthreads();
        if (threadIdx.x == 0) lens[blockIdx.x] = cnt;
    }

    int idx = blockIdx.x * blockDim.x + threadIdx.x;
    int stride = gridDim.x * blockDim.x;
    const int n0 = NWID * EE;       // 1024*128, KC0 = 4
    const int n1 = NWID * 256;      // 1024*256, KC1 = 8
    for (int i = idx; i < n0; i += stride) {
        int j8 = i & 7; int ln = (i >> 3) & 63; int rest = i >> 9;
        int kc = rest & 3; int ntg = rest >> 2;
        int lr = ln & 15, lq = ln >> 4;
        int n = ntg * 16 + lr;
        int k = kc * 32 + lq * 8 + j8;
        float v = (n < 512) ? wi0f[n * 128 + k] : wi0b[(n - 512) * 128 + k];
        WP0[i] = (half_t)v;
    }
    for (int i = idx; i < n1; i += stride) {
        int j8 = i & 7; int ln = (i >> 3) & 63; int rest = i >> 9;
        int kc = rest & 7; int ntg = rest >> 3;
        int lr = ln & 15, lq = ln >> 4;
        int n = ntg * 16 + lr;
        int k = kc * 32 + lq * 8 + j8;
        float v = (n < 512) ? wi1f[n * 256 + k] : wi1b[(n - 512) * 256 + k];
        WP1[i] = (half_t)v;
    }
    for (int i = idx; i < KK * 256; i += stride)
        WO[i] = (half_t)w_out[i];
    // embedding gather -> fp16 (16 half8 groups per token)
    for (int i = idx; i < MTOT * 16; i += stride) {
        int bt = i >> 4;
        int c  = (i & 15) * 8;
        int xi = x[bt];
        const float4* src = (const float4*)(embed + (size_t)xi * EE + c);
        float4 a = src[0], b = src[1];
        half8_t o;
        o[0] = (half_t)a.x; o[1] = (half_t)a.y; o[2] = (half_t)a.z; o[3] = (half_t)a.w;
        o[4] = (half_t)b.x; o[5] = (half_t)b.y; o[6] = (half_t)b.z; o[7] = (half_t)b.w;
        *(half8_t*)(e16 + (size_t)bt * EE + c) = o;
    }
}

// ---------------------------------------------------------------- MFMA GEMM (R13: M=128/block, 2 m-tiles/wave)
__global__ __launch_bounds__(256, 2) void k_gemm(const half_t* __restrict__ A,
                                                 const half_t* __restrict__ WP,
                                                 const float* __restrict__ bias_f,
                                                 const float* __restrict__ bias_b,
                                                 const int* __restrict__ lens,
                                                 half_t* __restrict__ C, int Kd) {
    {
        int t0 = (blockIdx.x * 128) & 511;
        if (t0 >= lens[blockIdx.x >> 2]) return;   // whole 128-token block is padding
    }
    const int KC = Kd >> 5;
    int wave = threadIdx.x >> 6;
    int lane = threadIdx.x & 63;
    int m0 = blockIdx.x * 128 + wave * 32;      // 2 m-tiles: m0, m0+16
    int dir = blockIdx.y >> 1;
    int cg  = blockIdx.y & 1;
    int lr = lane & 15;
    int lq = lane >> 4;

    float4_t acc0[16], acc1[16];
    #pragma unroll
    for (int i = 0; i < 16; i++) {
        acc0[i] = (float4_t){0.f, 0.f, 0.f, 0.f};
        acc1[i] = (float4_t){0.f, 0.f, 0.f, 0.f};
    }

    const half_t* Arow0 = A + (size_t)(m0 + lr) * Kd + lq * 8;
    const half_t* Arow1 = Arow0 + (size_t)16 * Kd;
    const int ntile0 = dir * 32 + cg * 4;
    const half_t* Wbase = WP + ((size_t)ntile0 * KC * 64 + lane) * 8;

    for (int kc = 0; kc < KC; kc++) {
        half8_t af0 = *(const half8_t*)(Arow0 + kc * 32);
        half8_t af1 = *(const half8_t*)(Arow1 + kc * 32);
        #pragma unroll
        for (int nt = 0; nt < 16; nt++) {
            int g = nt >> 2, sub = nt & 3;
            half8_t bf = *(const half8_t*)(Wbase + (((size_t)(g * 8 + sub) * KC + kc) << 9));
            acc0[nt] = __builtin_amdgcn_mfma_f32_16x16x32_f16(af0, bf, acc0[nt], 0, 0, 0);
            acc1[nt] = __builtin_amdgcn_mfma_f32_16x16x32_f16(af1, bf, acc1[nt], 0, 0, 0);
        }
    }

    const float* bias = dir ? bias_b : bias_f;
    char* Crow = (char*)C + dir * 1024 + (size_t)(cg * 64) * 8;
    #pragma unroll
    for (int sub = 0; sub < 4; sub++) {
        int cbase = cg * 64 + sub * 16 + lr;
        float b0 = bias[cbase];
        float b1 = bias[128 + cbase];
        float b2 = bias[256 + cbase];
        float b3 = bias[384 + cbase];
        #pragma unroll
        for (int i = 0; i < 4; i++) {
            int m = m0 + lq * 4 + i;
            half4_t o;
            o[0] = (half_t)(acc0[0 * 4 + sub][i] + b0);
            o[1] = (half_t)(acc0[1 * 4 + sub][i] + b1);
            o[2] = (half_t)(acc0[2 * 4 + sub][i] + b2);
            o[3] = (half_t)(acc0[3 * 4 + sub][i] + b3);
            *(half4_t*)(Crow + (size_t)m * 2048 + (sub * 16 + lr) * 8) = o;
            half4_t o2;
            o2[0] = (half_t)(acc1[0 * 4 + sub][i] + b0);
            o2[1] = (half_t)(acc1[1 * 4 + sub][i] + b1);
            o2[2] = (half_t)(acc1[2 * 4 + sub][i] + b2);
            o2[3] = (half_t)(acc1[3 * 4 + sub][i] + b3);
            *(half4_t*)(Crow + (size_t)(m + 16) * 2048 + (sub * 16 + lr) * 8) = o2;
        }
    }
}

// ---------------------------------------------------------------- recurrent LSTM via MFMA, 4 chains per block, 32 blocks
// (R7 version — 8 waves/block, 2 waves/SIMD TLP covers per-wave stalls.)
__global__ __launch_bounds__(512, 1) void k_lstm(const half_t* __restrict__ zbuf,
                                                 const float* __restrict__ wh_f,
                                                 const float* __restrict__ wh_b,
                                                 const int* __restrict__ lens,
                                                 half_t* __restrict__ hout) {
    const int grp  = blockIdx.x >> 1;     // 16 seq-groups of 4
    const int dir  = blockIdx.x & 1;
    const int tid  = threadIdx.x;
    const int wv   = tid >> 6;
    const int lane = tid & 63;
    const int q    = lane >> 4;           // k-quad / D-row-quad
    const int col  = lane & 15;           // B column
    const int s    = col & 3;             // seq within group
    const int ii   = col >> 2;            // which M-tile this lane activates
    const int b    = grp * 4 + s;
    const int Lb   = lens[b];
    const int maxL = lens[grp * 4];       // lengths sorted descending
    const float* wh = dir ? wh_b : wh_f;

    __shared__ half_t hb[2][512];   // [buf][ck*128 + (s*4+q)*8 + j]

    half8_t a0[4], a1[4], a2[4], a3[4];
    #pragma unroll
    for (int i = 0; i < 4; i++) {
        int r = wv * 64 + i * 16 + col;            // interleaved row; A[m=col][k=q*8+j]
        int orow = (r & 3) * 128 + (r >> 2);       // original wh row = gate*128 + cell
        #pragma unroll
        for (int ck = 0; ck < 4; ck++) {
            const float4* src = (const float4*)(wh + (size_t)orow * 128 + ck * 32 + q * 8);
            float4 f0 = src[0], f1 = src[1];
            half8_t h8;
            h8[0] = (half_t)f0.x; h8[1] = (half_t)f0.y; h8[2] = (half_t)f0.z; h8[3] = (half_t)f0.w;
            h8[4] = (half_t)f1.x; h8[5] = (half_t)f1.y; h8[6] = (half_t)f1.z; h8[7] = (half_t)f1.w;
            if (i == 0) a0[ck] = h8;
            else if (i == 1) a1[ck] = h8;
            else if (i == 2) a2[ck] = h8;
            else a3[ck] = h8;
        }
    }

    hb[0][tid] = (half_t)0.f;   // zero h(0) buffer

    const int cell = wv * 16 + ii * 4 + q;
    const int woff = (cell >> 5) * 128 + (s * 4 + ((cell >> 3) & 3)) * 8 + (cell & 7);
    const int roff = (s * 4 + q) * 8;     // B-frag read offset (+ ck*128)

    const bool s1 = (ii == 1), s2 = (ii == 2), s3 = (ii == 3);

    float c = 0.f;
    const char* zb8  = (const char*)zbuf + dir * 1024;   // + per-lane u32 byte offset
    char*       hob8 = (char*)hout + dir * 256;

    const int zdelta = dir ? -2048 : 2048;
    const int hdelta = dir ? -512 : 512;

    int t0 = dir ? (Lb - 1) : 0;
    int t1 = dir ? (Lb - 2) : 1;          // Lb >= 256, safe
    half4_t z1 = *(const half4_t*)(zb8 + (unsigned)((b * TT + t0) * 2048 + cell * 8));
    half4_t z2 = *(const half4_t*)(zb8 + (unsigned)((b * TT + t1) * 2048 + cell * 8));

    int zoff = (b * TT + (dir ? (Lb - 3) : 2)) * 2048 + cell * 8;
    int hoff = (b * TT + t0) * 512 + cell * 2;
    const unsigned deadoff = (unsigned)((b * TT + 511) * 512 + cell * 2);

    __syncthreads();

    const int maxL2 = (maxL + 1) & ~1;

#define LSTM_STEP(RB, ZC, T)                                                      \
    {                                                                             \
        half8_t bf0 = *(const half8_t*)&hb[RB][roff];                             \
        half8_t bf1 = *(const half8_t*)&hb[RB][128 + roff];                       \
        half8_t bf2 = *(const half8_t*)&hb[RB][256 + roff];                       \
        half8_t bf3 = *(const half8_t*)&hb[RB][384 + roff];                       \
        float4_t A0 = (float4_t){0.f, 0.f, 0.f, 0.f};                             \
        float4_t A1 = (float4_t){0.f, 0.f, 0.f, 0.f};                             \
        float4_t A2 = (float4_t){0.f, 0.f, 0.f, 0.f};                             \
        float4_t A3 = (float4_t){0.f, 0.f, 0.f, 0.f};                             \
        A0 = __builtin_amdgcn_mfma_f32_16x16x32_f16(a0[0], bf0, A0, 0, 0, 0);     \
        A1 = __builtin_amdgcn_mfma_f32_16x16x32_f16(a1[0], bf0, A1, 0, 0, 0);     \
        A2 = __builtin_amdgcn_mfma_f32_16x16x32_f16(a2[0], bf0, A2, 0, 0, 0);     \
        A3 = __builtin_amdgcn_mfma_f32_16x16x32_f16(a3[0], bf0, A3, 0, 0, 0);     \
        A0 = __builtin_amdgcn_mfma_f32_16x16x32_f16(a0[1], bf1, A0, 0, 0, 0);     \
        A1 = __builtin_amdgcn_mfma_f32_16x16x32_f16(a1[1], bf1, A1, 0, 0, 0);     \
        A2 = __builtin_amdgcn_mfma_f32_16x16x32_f16(a2[1], bf1, A2, 0, 0, 0);     \
        A3 = __builtin_amdgcn_mfma_f32_16x16x32_f16(a3[1], bf1, A3, 0, 0, 0);     \
        A0 = __builtin_amdgcn_mfma_f32_16x16x32_f16(a0[2], bf2, A0, 0, 0, 0);     \
        A1 = __builtin_amdgcn_mfma_f32_16x16x32_f16(a1[2], bf2, A1, 0, 0, 0);     \
        A2 = __builtin_amdgcn_mfma_f32_16x16x32_f16(a2[2], bf2, A2, 0, 0, 0);     \
        A3 = __builtin_amdgcn_mfma_f32_16x16x32_f16(a3[2], bf2, A3, 0, 0, 0);     \
        A0 = __builtin_amdgcn_mfma_f32_16x16x32_f16(a0[3], bf3, A0, 0, 0, 0);     \
        A1 = __builtin_amdgcn_mfma_f32_16x16x32_f16(a1[3], bf3, A1, 0, 0, 0);     \
        A2 = __builtin_amdgcn_mfma_f32_16x16x32_f16(a2[3], bf3, A2, 0, 0, 0);     \
        A3 = __builtin_amdgcn_mfma_f32_16x16x32_f16(a3[3], bf3, A3, 0, 0, 0);     \
        float g0 = s1 ? A1[0] : (s2 ? A2[0] : (s3 ? A3[0] : A0[0]));              \
        float g1 = s1 ? A1[1] : (s2 ? A2[1] : (s3 ? A3[1] : A0[1]));              \
        float g2 = s1 ? A1[2] : (s2 ? A2[2] : (s3 ? A3[2] : A0[2]));              \
        float g3 = s1 ? A1[3] : (s2 ? A2[3] : (s3 ? A3[3] : A0[3]));              \
        float zi = g0 + (float)ZC[0];                                             \
        float zf = g1 + (float)ZC[1];                                             \
        float zg = g2 + (float)ZC[2];                                             \
        float zo = g3 + (float)ZC[3];                                             \
        ZC = *(const half4_t*)(zb8 + (unsigned)zoff);   /* reload: z(T+2) */      \
        zoff += zdelta;                                                           \
        zoff = zoff < 0 ? 0 : zoff;                                               \
        float si = fast_sigmoid(zi);                                              \
        float sf = fast_sigmoid(zf);                                              \
        float so = fast_sigmoid(zo);                                              \
        float tg = fast_tanh(zg);                                                 \
        c = sf * c + si * tg;                                                     \
        float th = fast_tanh(c);                                                  \
        half_t hh = (half_t)(so * th);                                            \
        hb[RB ^ 1][woff] = hh;                                                    \
        unsigned soff = ((T) < Lb) ? (unsigned)hoff : deadoff;                    \
        *(half_t*)(hob8 + soff) = hh;   /* fire-and-forget */                     \
        hoff += hdelta;                                                           \
        lds_barrier();                                                            \
    }

    for (int t = 0; t < maxL2; t += 2) {
        LSTM_STEP(0, z1, t)
        LSTM_STEP(1, z2, t + 1)
    }
#undef LSTM_STEP
}

// ---------------------------------------------------------------- fused logits + CRF (one block of 256 thr per sequence)
// Phase 1: 4 waves compute logits[t,k] via MFMA into LDS (fp16, 32 KB).
// Phase 2: gold score partial-reduced by all waves.
// Phase 3: wave 0 runs the 511-step recursion entirely from LDS/registers.
__global__ __launch_bounds__(256) void k_crf(const half_t* __restrict__ h1,
                                             const half_t* __restrict__ WO,
                                             const float* __restrict__ b_out,
                                             const float* __restrict__ trans,
                                             const int* __restrict__ y,
                                             const int* __restrict__ lens,
                                             float* __restrict__ out) {
    const int b = blockIdx.x;
    const int tid = threadIdx.x;
    const int wv = tid >> 6;
    const int lane = tid & 63;
    const int lr = lane & 15;
    const int lq = lane >> 4;
    const int Lb = lens[b];

    __shared__ half_t LG[TT * KK];   // 32 KB: logits fp16 [t][k]
    __shared__ float TR[32][33];
    __shared__ float gpart[4];

    for (int i = tid; i < 1024; i += 256) TR[i >> 5][i & 31] = trans[i];

    // ---- phase 1: logits = h1 @ WO^T + b_out for tiles covering t < Lb
    // B-frags (WO) hoisted: 2 n-tiles x 8 kc
    half8_t bf[2][8];
    #pragma unroll
    for (int nt = 0; nt < 2; nt++)
        #pragma unroll
        for (int kc = 0; kc < 8; kc++)
            bf[nt][kc] = *(const half8_t*)(WO + (size_t)(nt * 16 + lr) * 256 + kc * 32 + lq * 8);
    float bias0 = b_out[lr];
    float bias1 = b_out[16 + lr];

    const int ntiles = (Lb + 15) >> 4;
    for (int tile = wv; tile < ntiles; tile += 4) {
        const half_t* Arow = h1 + (size_t)(b * TT + tile * 16 + lr) * 256 + lq * 8;
        float4_t acc0 = (float4_t){0.f, 0.f, 0.f, 0.f};
        float4_t acc1 = (float4_t){0.f, 0.f, 0.f, 0.f};
        #pragma unroll
        for (int kc = 0; kc < 8; kc++) {
            half8_t af = *(const half8_t*)(Arow + kc * 32);
            acc0 = __builtin_amdgcn_mfma_f32_16x16x32_f16(af, bf[0][kc], acc0, 0, 0, 0);
            acc1 = __builtin_amdgcn_mfma_f32_16x16x32_f16(af, bf[1][kc], acc1, 0, 0, 0);
        }
        #pragma unroll
        for (int i = 0; i < 4; i++) {
            int t = tile * 16 + lq * 4 + i;
            LG[t * KK + lr]      = (half_t)(acc0[i] + bias0);
            LG[t * KK + 16 + lr] = (half_t)(acc1[i] + bias1);
        }
    }
    __syncthreads();

    // ---- phase 2: gold score (all 256 threads)
    const int* yb = y + b * (TT + 1);
    float g = 0.f;
    for (int t = tid; t < Lb; t += 256) {
        int yt = yb[t], yt1 = yb[t + 1];
        g += (float)LG[t * KK + yt1] + TR[yt1][yt];
    }
    #pragma unroll
    for (int s = 1; s < 64; s <<= 1) g += __shfl_xor(g, s);
    if (lane == 0) gpart[wv] = g;
    __syncthreads();

    if (wv != 0) return;   // waves 1-3 done (no barriers after this point)

    // ---- phase 3: recursion (wave 0 only)
    const int k = lane & 31;
    float gold = gpart[0] + gpart[1] + gpart[2] + gpart[3] + TR[3][yb[Lb]];

    float et[32];
    const float* trow = trans + k * 32;
    #pragma unroll
    for (int j = 0; j < 32; j++) et[j] = __expf(trow[j]);   // exp(-10000) -> 0

    float score = (float)LG[k] + TR[k][2];   // t=0 analytic (SOS=2)

    float lg_cur = (float)LG[KK + k];
    for (int t = 1; t < Lb; t++) {
        float lg_use = lg_cur;
        int tn = (t + 1 < TT) ? (t + 1) : t;
        lg_cur = (float)LG[tn * KK + k];     // prefetch t+1 (LDS, independent of chain)
        float m = readlane_f(score, 4);      // tag 4 always live; live spread << 88
        float P = __expf(score - m);
        float a0 = 0.f, a1 = 0.f, a2 = 0.f, a3 = 0.f;
        #pragma unroll
        for (int j = 0; j < 8; j++) {
            a0 = fmaf(et[j],      readlane_f(P, j),      a0);
            a1 = fmaf(et[j + 8],  readlane_f(P, j + 8),  a1);
            a2 = fmaf(et[j + 16], readlane_f(P, j + 16), a2);
            a3 = fmaf(et[j + 24], readlane_f(P, j + 24), a3);
        }
        score = lg_use + m + __logf((a0 + a1) + (a2 + a3));
    }

    float v = score + TR[3][k];
    float m2 = v;
    #pragma unroll
    for (int s = 1; s < 32; s <<= 1) m2 = fmaxf(m2, __shfl_xor(m2, s));
    float e = __expf(v - m2);
    #pragma unroll
    for (int s = 1; s < 32; s <<= 1) e += __shfl_xor(e, s);
    float logZ = m2 + __logf(e);

    if (lane == 0) out[b] = logZ - gold;
}

// ----------------------------------------------------------------
extern "C" void kernel_launch(void* const* d_in, const int* in_sizes, int n_in,
                              void* d_out, int out_size, void* d_ws, size_t ws_size,
                              hipStream_t stream) {
    const int*   x      = (const int*)d_in[0];
    const int*   y      = (const int*)d_in[1];
    const float* embed  = (const float*)d_in[2];
    const float* wi_l0f = (const float*)d_in[3];
    const float* wh_l0f = (const float*)d_in[4];
    const float* b_l0f  = (const float*)d_in[5];
    const float* wi_l0b = (const float*)d_in[6];
    const float* wh_l0b = (const float*)d_in[7];
    const float* b_l0b  = (const float*)d_in[8];
    const float* wi_l1f = (const float*)d_in[9];
    const float* wh_l1f = (const float*)d_in[10];
    const float* b_l1f  = (const float*)d_in[11];
    const float* wi_l1b = (const float*)d_in[12];
    const float* wh_l1b = (const float*)d_in[13];
    const float* b_l1b  = (const float*)d_in[14];
    const float* w_out  = (const float*)d_in[15];
    const float* b_out  = (const float*)d_in[16];
    const float* trans  = (const float*)d_in[17];
    float* out = (float*)d_out;

    char* base = (char*)d_ws;
    size_t off = 0;
    auto take = [&](size_t bytes) -> char* {
        char* r = base + off;
        off = (off + bytes + 255) & ~(size_t)255;
        return r;
    };
    half_t* zA  = (half_t*)take((size_t)MTOT * NWID * 2);  // 64 MiB
    half_t* h0  = (half_t*)take((size_t)MTOT * 256 * 2);   // 16 MiB
    half_t* h1  = (half_t*)take((size_t)MTOT * 256 * 2);   // 16 MiB
    half_t* e16 = (half_t*)take((size_t)MTOT * EE * 2);    // 8 MiB
    half_t* WP0 = (half_t*)take((size_t)NWID * EE * 2);
    half_t* WP1 = (half_t*)take((size_t)NWID * 256 * 2);
    half_t* WO  = (half_t*)take((size_t)KK * 256 * 2);
    int*    lens = (int*)take(BB * 4);

    k_pack<<<512, 256, 0, stream>>>(wi_l0f, wi_l0b, wi_l1f, wi_l1b, w_out, x, embed,
                                    WP0, WP1, WO, e16, lens);
    k_gemm<<<dim3(MTOT / 128, 4), 256, 0, stream>>>(e16, WP0, b_l0f, b_l0b, lens, zA, 128);
    k_lstm<<<32, 512, 0, stream>>>(zA, wh_l0f, wh_l0b, lens, h0);
    k_gemm<<<dim3(MTOT / 128, 4), 256, 0, stream>>>(h0, WP1, b_l1f, b_l1b, lens, zA, 256);
    k_lstm<<<32, 512, 0, stream>>>(zA, wh_l1f, wh_l1b, lens, h1);
    k_crf<<<BB, 256, 0, stream>>>(h1, WO, b_out, trans, y, lens, out);
}

// Round 15
// 843.290 us; speedup vs baseline: 1.0177x; 1.0177x over previous
//
#include <hip/hip_runtime.h>

typedef _Float16 half_t;
typedef _Float16 half2_t __attribute__((ext_vector_type(2)));
typedef _Float16 half4_t __attribute__((ext_vector_type(4)));
typedef _Float16 half8_t __attribute__((ext_vector_type(8)));
typedef float float4_t __attribute__((ext_vector_type(4)));

// Problem constants
#define BB 64
#define TT 512
#define EE 128
#define HPP 128
#define KK 32
#define MTOT (BB*TT)     // 32768
#define NWID 1024        // stacked fwd(512)+bwd(512) gate rows, gate-interleaved per dir

// barrier that drains ONLY LDS ops (z prefetch + h global stores stay in flight)
__device__ __forceinline__ void lds_barrier() {
    asm volatile("s_waitcnt lgkmcnt(0)\n\ts_barrier" ::: "memory");
}

__device__ __forceinline__ float fast_sigmoid(float x) {
    return __builtin_amdgcn_rcpf(1.f + __expf(-x));     // v_exp + v_rcp, no div sequence
}
__device__ __forceinline__ float fast_tanh(float x) {
    return 1.f - 2.f * __builtin_amdgcn_rcpf(__expf(2.f * x) + 1.f);
}
__device__ __forceinline__ float readlane_f(float v, int lane) {
    return __builtin_bit_cast(float, __builtin_amdgcn_readlane(__builtin_bit_cast(int, v), lane));
}

// ---------------------------------------------------------------- pack weights fp32->fp16 + embed gather + lengths (merged)
__global__ void k_pack(const float* __restrict__ wi0f, const float* __restrict__ wi0b,
                       const float* __restrict__ wi1f, const float* __restrict__ wi1b,
                       const float* __restrict__ w_out,
                       const int* __restrict__ x, const float* __restrict__ embed,
                       half_t* __restrict__ WP0, half_t* __restrict__ WP1,
                       half_t* __restrict__ WO, half_t* __restrict__ e16,
                       int* __restrict__ lens) {
    // lengths: blocks 0..63, one block per sequence
    if (blockIdx.x < BB) {
        __shared__ int cnt;
        if (threadIdx.x == 0) cnt = 0;
        __syncthreads();
        int local = 0;
        for (int t = threadIdx.x; t < TT; t += blockDim.x)
            local += (x[blockIdx.x * TT + t] > 0) ? 1 : 0;
        atomicAdd(&cnt, local);
        __syncthreads();
        if (threadIdx.x == 0) lens[blockIdx.x] = cnt;
    }

    int idx = blockIdx.x * blockDim.x + threadIdx.x;
    int stride = gridDim.x * blockDim.x;
    const int n0 = NWID * EE;       // 1024*128, KC0 = 4
    const int n1 = NWID * 256;      // 1024*256, KC1 = 8
    for (int i = idx; i < n0; i += stride) {
        int j8 = i & 7; int ln = (i >> 3) & 63; int rest = i >> 9;
        int kc = rest & 3; int ntg = rest >> 2;
        int lr = ln & 15, lq = ln >> 4;
        int n = ntg * 16 + lr;
        int k = kc * 32 + lq * 8 + j8;
        float v = (n < 512) ? wi0f[n * 128 + k] : wi0b[(n - 512) * 128 + k];
        WP0[i] = (half_t)v;
    }
    for (int i = idx; i < n1; i += stride) {
        int j8 = i & 7; int ln = (i >> 3) & 63; int rest = i >> 9;
        int kc = rest & 7; int ntg = rest >> 3;
        int lr = ln & 15, lq = ln >> 4;
        int n = ntg * 16 + lr;
        int k = kc * 32 + lq * 8 + j8;
        float v = (n < 512) ? wi1f[n * 256 + k] : wi1b[(n - 512) * 256 + k];
        WP1[i] = (half_t)v;
    }
    for (int i = idx; i < KK * 256; i += stride)
        WO[i] = (half_t)w_out[i];
    // embedding gather -> fp16 (16 half8 groups per token)
    for (int i = idx; i < MTOT * 16; i += stride) {
        int bt = i >> 4;
        int c  = (i & 15) * 8;
        int xi = x[bt];
        const float4* src = (const float4*)(embed + (size_t)xi * EE + c);
        float4 a = src[0], b = src[1];
        half8_t o;
        o[0] = (half_t)a.x; o[1] = (half_t)a.y; o[2] = (half_t)a.z; o[3] = (half_t)a.w;
        o[4] = (half_t)b.x; o[5] = (half_t)b.y; o[6] = (half_t)b.z; o[7] = (half_t)b.w;
        *(half8_t*)(e16 + (size_t)bt * EE + c) = o;
    }
}

// ---------------------------------------------------------------- MFMA GEMM (M=128/block, 2 m-tiles/wave)
__global__ __launch_bounds__(256, 2) void k_gemm(const half_t* __restrict__ A,
                                                 const half_t* __restrict__ WP,
                                                 const float* __restrict__ bias_f,
                                                 const float* __restrict__ bias_b,
                                                 const int* __restrict__ lens,
                                                 half_t* __restrict__ C, int Kd) {
    {
        int t0 = (blockIdx.x * 128) & 511;
        if (t0 >= lens[blockIdx.x >> 2]) return;   // whole 128-token block is padding
    }
    const int KC = Kd >> 5;
    int wave = threadIdx.x >> 6;
    int lane = threadIdx.x & 63;
    int m0 = blockIdx.x * 128 + wave * 32;      // 2 m-tiles: m0, m0+16
    int dir = blockIdx.y >> 1;
    int cg  = blockIdx.y & 1;
    int lr = lane & 15;
    int lq = lane >> 4;

    float4_t acc0[16], acc1[16];
    #pragma unroll
    for (int i = 0; i < 16; i++) {
        acc0[i] = (float4_t){0.f, 0.f, 0.f, 0.f};
        acc1[i] = (float4_t){0.f, 0.f, 0.f, 0.f};
    }

    const half_t* Arow0 = A + (size_t)(m0 + lr) * Kd + lq * 8;
    const half_t* Arow1 = Arow0 + (size_t)16 * Kd;
    const int ntile0 = dir * 32 + cg * 4;
    const half_t* Wbase = WP + ((size_t)ntile0 * KC * 64 + lane) * 8;

    for (int kc = 0; kc < KC; kc++) {
        half8_t af0 = *(const half8_t*)(Arow0 + kc * 32);
        half8_t af1 = *(const half8_t*)(Arow1 + kc * 32);
        #pragma unroll
        for (int nt = 0; nt < 16; nt++) {
            int g = nt >> 2, sub = nt & 3;
            half8_t bf = *(const half8_t*)(Wbase + (((size_t)(g * 8 + sub) * KC + kc) << 9));
            acc0[nt] = __builtin_amdgcn_mfma_f32_16x16x32_f16(af0, bf, acc0[nt], 0, 0, 0);
            acc1[nt] = __builtin_amdgcn_mfma_f32_16x16x32_f16(af1, bf, acc1[nt], 0, 0, 0);
        }
    }

    const float* bias = dir ? bias_b : bias_f;
    char* Crow = (char*)C + dir * 1024 + (size_t)(cg * 64) * 8;
    #pragma unroll
    for (int sub = 0; sub < 4; sub++) {
        int cbase = cg * 64 + sub * 16 + lr;
        float b0 = bias[cbase];
        float b1 = bias[128 + cbase];
        float b2 = bias[256 + cbase];
        float b3 = bias[384 + cbase];
        #pragma unroll
        for (int i = 0; i < 4; i++) {
            int m = m0 + lq * 4 + i;
            half4_t o;
            o[0] = (half_t)(acc0[0 * 4 + sub][i] + b0);
            o[1] = (half_t)(acc0[1 * 4 + sub][i] + b1);
            o[2] = (half_t)(acc0[2 * 4 + sub][i] + b2);
            o[3] = (half_t)(acc0[3 * 4 + sub][i] + b3);
            *(half4_t*)(Crow + (size_t)m * 2048 + (sub * 16 + lr) * 8) = o;
            half4_t o2;
            o2[0] = (half_t)(acc1[0 * 4 + sub][i] + b0);
            o2[1] = (half_t)(acc1[1 * 4 + sub][i] + b1);
            o2[2] = (half_t)(acc1[2 * 4 + sub][i] + b2);
            o2[3] = (half_t)(acc1[3 * 4 + sub][i] + b3);
            *(half4_t*)(Crow + (size_t)(m + 16) * 2048 + (sub * 16 + lr) * 8) = o2;
        }
    }
}

// ---------------------------------------------------------------- recurrent LSTM via MFMA, 4 chains per block, 32 blocks
// (R7 structure — 8 waves/block, 2 waves/SIMD TLP covers per-wave stalls.)
__global__ __launch_bounds__(512, 1) void k_lstm(const half_t* __restrict__ zbuf,
                                                 const float* __restrict__ wh_f,
                                                 const float* __restrict__ wh_b,
                                                 const int* __restrict__ lens,
                                                 half_t* __restrict__ hout) {
    const int grp  = blockIdx.x >> 1;     // 16 seq-groups of 4
    const int dir  = blockIdx.x & 1;
    const int tid  = threadIdx.x;
    const int wv   = tid >> 6;
    const int lane = tid & 63;
    const int q    = lane >> 4;           // k-quad / D-row-quad
    const int col  = lane & 15;           // B column
    const int s    = col & 3;             // seq within group
    const int ii   = col >> 2;            // which M-tile this lane activates
    const int b    = grp * 4 + s;
    const int Lb   = lens[b];
    const int maxL = lens[grp * 4];       // lengths sorted descending
    const float* wh = dir ? wh_b : wh_f;

    __shared__ half_t hb[2][512];   // [buf][ck*128 + (s*4+q)*8 + j]

    half8_t a0[4], a1[4], a2[4], a3[4];
    #pragma unroll
    for (int i = 0; i < 4; i++) {
        int r = wv * 64 + i * 16 + col;            // interleaved row; A[m=col][k=q*8+j]
        int orow = (r & 3) * 128 + (r >> 2);       // original wh row = gate*128 + cell
        #pragma unroll
        for (int ck = 0; ck < 4; ck++) {
            const float4* src = (const float4*)(wh + (size_t)orow * 128 + ck * 32 + q * 8);
            float4 f0 = src[0], f1 = src[1];
            half8_t h8;
            h8[0] = (half_t)f0.x; h8[1] = (half_t)f0.y; h8[2] = (half_t)f0.z; h8[3] = (half_t)f0.w;
            h8[4] = (half_t)f1.x; h8[5] = (half_t)f1.y; h8[6] = (half_t)f1.z; h8[7] = (half_t)f1.w;
            if (i == 0) a0[ck] = h8;
            else if (i == 1) a1[ck] = h8;
            else if (i == 2) a2[ck] = h8;
            else a3[ck] = h8;
        }
    }

    hb[0][tid] = (half_t)0.f;   // zero h(0) buffer

    const int cell = wv * 16 + ii * 4 + q;
    const int woff = (cell >> 5) * 128 + (s * 4 + ((cell >> 3) & 3)) * 8 + (cell & 7);
    const int roff = (s * 4 + q) * 8;     // B-frag read offset (+ ck*128)

    const bool s1 = (ii == 1), s2 = (ii == 2), s3 = (ii == 3);

    float c = 0.f;
    const char* zb8  = (const char*)zbuf + dir * 1024;   // + per-lane u32 byte offset
    char*       hob8 = (char*)hout + dir * 256;

    const int zdelta = dir ? -2048 : 2048;
    const int hdelta = dir ? -512 : 512;

    int t0 = dir ? (Lb - 1) : 0;
    int t1 = dir ? (Lb - 2) : 1;          // Lb >= 256, safe
    half4_t z1 = *(const half4_t*)(zb8 + (unsigned)((b * TT + t0) * 2048 + cell * 8));
    half4_t z2 = *(const half4_t*)(zb8 + (unsigned)((b * TT + t1) * 2048 + cell * 8));

    int zoff = (b * TT + (dir ? (Lb - 3) : 2)) * 2048 + cell * 8;
    int hoff = (b * TT + t0) * 512 + cell * 2;
    const unsigned deadoff = (unsigned)((b * TT + 511) * 512 + cell * 2);

    __syncthreads();

    const int maxL2 = (maxL + 1) & ~1;

#define LSTM_STEP(RB, ZC, T)                                                      \
    {                                                                             \
        half8_t bf0 = *(const half8_t*)&hb[RB][roff];                             \
        half8_t bf1 = *(const half8_t*)&hb[RB][128 + roff];                       \
        half8_t bf2 = *(const half8_t*)&hb[RB][256 + roff];                       \
        half8_t bf3 = *(const half8_t*)&hb[RB][384 + roff];                       \
        float4_t A0 = (float4_t){0.f, 0.f, 0.f, 0.f};                             \
        float4_t A1 = (float4_t){0.f, 0.f, 0.f, 0.f};                             \
        float4_t A2 = (float4_t){0.f, 0.f, 0.f, 0.f};                             \
        float4_t A3 = (float4_t){0.f, 0.f, 0.f, 0.f};                             \
        A0 = __builtin_amdgcn_mfma_f32_16x16x32_f16(a0[0], bf0, A0, 0, 0, 0);     \
        A1 = __builtin_amdgcn_mfma_f32_16x16x32_f16(a1[0], bf0, A1, 0, 0, 0);     \
        A2 = __builtin_amdgcn_mfma_f32_16x16x32_f16(a2[0], bf0, A2, 0, 0, 0);     \
        A3 = __builtin_amdgcn_mfma_f32_16x16x32_f16(a3[0], bf0, A3, 0, 0, 0);     \
        A0 = __builtin_amdgcn_mfma_f32_16x16x32_f16(a0[1], bf1, A0, 0, 0, 0);     \
        A1 = __builtin_amdgcn_mfma_f32_16x16x32_f16(a1[1], bf1, A1, 0, 0, 0);     \
        A2 = __builtin_amdgcn_mfma_f32_16x16x32_f16(a2[1], bf1, A2, 0, 0, 0);     \
        A3 = __builtin_amdgcn_mfma_f32_16x16x32_f16(a3[1], bf1, A3, 0, 0, 0);     \
        A0 = __builtin_amdgcn_mfma_f32_16x16x32_f16(a0[2], bf2, A0, 0, 0, 0);     \
        A1 = __builtin_amdgcn_mfma_f32_16x16x32_f16(a1[2], bf2, A1, 0, 0, 0);     \
        A2 = __builtin_amdgcn_mfma_f32_16x16x32_f16(a2[2], bf2, A2, 0, 0, 0);     \
        A3 = __builtin_amdgcn_mfma_f32_16x16x32_f16(a3[2], bf2, A3, 0, 0, 0);     \
        A0 = __builtin_amdgcn_mfma_f32_16x16x32_f16(a0[3], bf3, A0, 0, 0, 0);     \
        A1 = __builtin_amdgcn_mfma_f32_16x16x32_f16(a1[3], bf3, A1, 0, 0, 0);     \
        A2 = __builtin_amdgcn_mfma_f32_16x16x32_f16(a2[3], bf3, A2, 0, 0, 0);     \
        A3 = __builtin_amdgcn_mfma_f32_16x16x32_f16(a3[3], bf3, A3, 0, 0, 0);     \
        float g0 = s1 ? A1[0] : (s2 ? A2[0] : (s3 ? A3[0] : A0[0]));              \
        float g1 = s1 ? A1[1] : (s2 ? A2[1] : (s3 ? A3[1] : A0[1]));              \
        float g2 = s1 ? A1[2] : (s2 ? A2[2] : (s3 ? A3[2] : A0[2]));              \
        float g3 = s1 ? A1[3] : (s2 ? A2[3] : (s3 ? A3[3] : A0[3]));              \
        float zi = g0 + (float)ZC[0];                                             \
        float zf = g1 + (float)ZC[1];                                             \
        float zg = g2 + (float)ZC[2];                                             \
        float zo = g3 + (float)ZC[3];                                             \
        ZC = *(const half4_t*)(zb8 + (unsigned)zoff);   /* reload: z(T+2) */      \
        zoff += zdelta;                                                           \
        zoff = zoff < 0 ? 0 : zoff;                                               \
        float si = fast_sigmoid(zi);                                              \
        float sf = fast_sigmoid(zf);                                              \
        float so = fast_sigmoid(zo);                                              \
        float tg = fast_tanh(zg);                                                 \
        c = sf * c + si * tg;                                                     \
        float th = fast_tanh(c);                                                  \
        half_t hh = (half_t)(so * th);                                            \
        hb[RB ^ 1][woff] = hh;                                                    \
        unsigned soff = ((T) < Lb) ? (unsigned)hoff : deadoff;                    \
        *(half_t*)(hob8 + soff) = hh;   /* fire-and-forget */                     \
        hoff += hdelta;                                                           \
        lds_barrier();                                                            \
    }

    for (int t = 0; t < maxL2; t += 2) {
        LSTM_STEP(0, z1, t)
        LSTM_STEP(1, z2, t + 1)
    }
#undef LSTM_STEP
}

// ---------------------------------------------------------------- output projection via MFMA (skip-pad)
__global__ __launch_bounds__(256) void k_logits(const half_t* __restrict__ h1,
                                                const half_t* __restrict__ WO,
                                                const float* __restrict__ b_out,
                                                const int* __restrict__ lens,
                                                float* __restrict__ logits) {
    {
        int t0 = (blockIdx.x * 64) & 511;
        if (t0 >= lens[blockIdx.x >> 3]) return;   // whole block is padding
    }
    int wave = threadIdx.x >> 6;
    int lane = threadIdx.x & 63;
    int m0 = blockIdx.x * 64 + wave * 16;
    int lr = lane & 15;
    int lq = lane >> 4;

    float4_t acc0 = (float4_t){0.f, 0.f, 0.f, 0.f};
    float4_t acc1 = (float4_t){0.f, 0.f, 0.f, 0.f};

    const half_t* Arow = h1 + (size_t)(m0 + lr) * 256 + lq * 8;
    const half_t* Brow = WO + (size_t)lr * 256 + lq * 8;

    #pragma unroll
    for (int k = 0; k < 256; k += 32) {
        half8_t af = *(const half8_t*)(Arow + k);
        half8_t b0 = *(const half8_t*)(Brow + k);
        half8_t b1 = *(const half8_t*)(Brow + 16 * 256 + k);
        acc0 = __builtin_amdgcn_mfma_f32_16x16x32_f16(af, b0, acc0, 0, 0, 0);
        acc1 = __builtin_amdgcn_mfma_f32_16x16x32_f16(af, b1, acc1, 0, 0, 0);
    }
    #pragma unroll
    for (int nt = 0; nt < 2; nt++) {
        int n = nt * 16 + lr;
        float bias = b_out[n];
        #pragma unroll
        for (int i = 0; i < 4; i++) {
            int m = m0 + lq * 4 + i;
            logits[(size_t)m * KK + n] = (nt == 0 ? acc0[i] : acc1[i]) + bias;
        }
    }
}

// ---------------------------------------------------------------- CRF forward + gold (one wave per sequence)
// P broadcast via 32 constant-index v_readlane + sgpr-operand fma — no LDS round trip.
__global__ __launch_bounds__(64) void k_crf(const float* __restrict__ logits,
                                            const float* __restrict__ trans,
                                            const int* __restrict__ y,
                                            const int* __restrict__ lens,
                                            float* __restrict__ out) {
    int b = blockIdx.x;
    int lane = threadIdx.x;
    int k = lane & 31;
    __shared__ float TR[32][33];

    for (int i = lane; i < 1024; i += 64) TR[i >> 5][i & 31] = trans[i];

    float et[32];
    const float* trow = trans + k * 32;
    #pragma unroll
    for (int j = 0; j < 32; j++) et[j] = __expf(trow[j]);   // exp(-10000) -> 0
    __syncthreads();

    int Lb = lens[b];
    const int* yb = y + b * (TT + 1);
    const float* lgb = logits + (size_t)(b * TT) * KK;

    float g = 0.f;
    for (int t = lane; t < Lb; t += 64) {
        int yt = yb[t], yt1 = yb[t + 1];
        g += lgb[(size_t)t * KK + yt1] + TR[yt1][yt];
    }
    #pragma unroll
    for (int s = 1; s < 64; s <<= 1) g += __shfl_xor(g, s);
    float gold = g + TR[3][yb[Lb]];

    float score = lgb[k] + TR[k][2];   // t=0 analytic (SOS=2)

    const float* lgp = lgb + KK + k;
    float lg_cur = *lgp;
    for (int t = 1; t < Lb; t++) {
        float lg_use = lg_cur;
        lgp += KK;
        lg_cur = *lgp;     // lg(t+1): harmless in-ws over-read at t=Lb-1
        float m = readlane_f(score, 4);    // tag 4 always live; live spread << 88
        float P = __expf(score - m);
        float a0 = 0.f, a1 = 0.f, a2 = 0.f, a3 = 0.f;
        #pragma unroll
        for (int j = 0; j < 8; j++) {
            a0 = fmaf(et[j],      readlane_f(P, j),      a0);
            a1 = fmaf(et[j + 8],  readlane_f(P, j + 8),  a1);
            a2 = fmaf(et[j + 16], readlane_f(P, j + 16), a2);
            a3 = fmaf(et[j + 24], readlane_f(P, j + 24), a3);
        }
        score = lg_use + m + __logf((a0 + a1) + (a2 + a3));
    }

    float v = score + TR[3][k];
    float m2 = v;
    #pragma unroll
    for (int s = 1; s < 32; s <<= 1) m2 = fmaxf(m2, __shfl_xor(m2, s));
    float e = __expf(v - m2);
    #pragma unroll
    for (int s = 1; s < 32; s <<= 1) e += __shfl_xor(e, s);
    float logZ = m2 + __logf(e);

    if (lane == 0) out[b] = logZ - gold;
}

// ----------------------------------------------------------------
extern "C" void kernel_launch(void* const* d_in, const int* in_sizes, int n_in,
                              void* d_out, int out_size, void* d_ws, size_t ws_size,
                              hipStream_t stream) {
    const int*   x      = (const int*)d_in[0];
    const int*   y      = (const int*)d_in[1];
    const float* embed  = (const float*)d_in[2];
    const float* wi_l0f = (const float*)d_in[3];
    const float* wh_l0f = (const float*)d_in[4];
    const float* b_l0f  = (const float*)d_in[5];
    const float* wi_l0b = (const float*)d_in[6];
    const float* wh_l0b = (const float*)d_in[7];
    const float* b_l0b  = (const float*)d_in[8];
    const float* wi_l1f = (const float*)d_in[9];
    const float* wh_l1f = (const float*)d_in[10];
    const float* b_l1f  = (const float*)d_in[11];
    const float* wi_l1b = (const float*)d_in[12];
    const float* wh_l1b = (const float*)d_in[13];
    const float* b_l1b  = (const float*)d_in[14];
    const float* w_out  = (const float*)d_in[15];
    const float* b_out  = (const float*)d_in[16];
    const float* trans  = (const float*)d_in[17];
    float* out = (float*)d_out;

    char* base = (char*)d_ws;
    size_t off = 0;
    auto take = [&](size_t bytes) -> char* {
        char* r = base + off;
        off = (off + bytes + 255) & ~(size_t)255;
        return r;
    };
    half_t* zA  = (half_t*)take((size_t)MTOT * NWID * 2);  // 64 MiB
    half_t* h0  = (half_t*)take((size_t)MTOT * 256 * 2);   // 16 MiB
    half_t* h1  = (half_t*)take((size_t)MTOT * 256 * 2);   // 16 MiB
    half_t* e16 = (half_t*)take((size_t)MTOT * EE * 2);    // 8 MiB
    float*  lg  = (float*)take((size_t)MTOT * KK * 4);     // 4 MiB
    half_t* WP0 = (half_t*)take((size_t)NWID * EE * 2);
    half_t* WP1 = (half_t*)take((size_t)NWID * 256 * 2);
    half_t* WO  = (half_t*)take((size_t)KK * 256 * 2);
    int*    lens = (int*)take(BB * 4);

    k_pack<<<512, 256, 0, stream>>>(wi_l0f, wi_l0b, wi_l1f, wi_l1b, w_out, x, embed,
                                    WP0, WP1, WO, e16, lens);
    k_gemm<<<dim3(MTOT / 128, 4), 256, 0, stream>>>(e16, WP0, b_l0f, b_l0b, lens, zA, 128);
    k_lstm<<<32, 512, 0, stream>>>(zA, wh_l0f, wh_l0b, lens, h0);
    k_gemm<<<dim3(MTOT / 128, 4), 256, 0, stream>>>(h0, WP1, b_l1f, b_l1b, lens, zA, 256);
    k_lstm<<<32, 512, 0, stream>>>(zA, wh_l1f, wh_l1b, lens, h1);
    k_logits<<<MTOT / 64, 256, 0, stream>>>(h1, WO, b_out, lens, lg);
    k_crf<<<BB, 64, 0, stream>>>(lg, trans, y, lens, out);
}